// Round 14
// baseline (20.376 us; speedup 1.0000x reference)
//
#include <hip/hip_runtime.h>

#define NN 4
#define CC 128
#define HH 64
#define WW 64
#define KK 5
#define K2 25
#define HUP 128
#define WUP 128
#define SLOTF 320                 // floats per channel slot (5 rows x 64)
#define HALFF (16 * SLOTF)        // floats per LDS half (16 channels)
#define OCH 65536                 // output byte stride of 1 channel

typedef int   v4i __attribute__((ext_vector_type(4)));
typedef float v2f __attribute__((ext_vector_type(2)));

__device__ void llvm_amdgcn_raw_buffer_store_v2f32(v2f data, v4i srsrc,
                                                   int voffset, int soffset,
                                                   int aux)
    __asm("llvm.amdgcn.raw.buffer.store.v2f32");

__device__ inline v4i make_srd(const void* p, unsigned bytes) {
  union { const void* p; unsigned u[2]; } a;
  a.p = p;
  v4i r;
  r.x = (int)a.u[0];
  r.y = (int)(a.u[1] & 0xffffu);  // base[47:32], stride=0
  r.z = (int)bytes;               // num_records in bytes
  r.w = 0x00020000;               // raw dword access
  return r;
}

// DPP wave shifts (R13-proven):
//   wave_shr:1 (0x138): lane w reads w-1 (chain zeros lanes 0,1 = vj-masked).
//   wave_shl:1 (0x130): lane w reads w+1 (chain zeros lanes 62,63).
__device__ inline float dpp_prev1(float x) {  // lane w <- w-1
  return __int_as_float(__builtin_amdgcn_update_dpp(
      0, __float_as_int(x), 0x138, 0xf, 0xf, true));
}
__device__ inline float dpp_next1(float x) {  // lane w <- w+1
  return __int_as_float(__builtin_amdgcn_update_dpp(
      0, __float_as_int(x), 0x130, 0xf, 0xf, true));
}

// grid: NN*HH*4 = 1024 blocks, 256 threads, 40 KB LDS -> 4 blocks/CU.
// block: cq = bid&3, h = (bid>>2)&63, n = bid>>8
// thread: w = t&63 (output cols 2w,2w+1), wv = t>>6 (wave = cg)
// channel of (half hx, iter ci): c = cq*32 + hx*16 + ci*4 + wv
//
// Split-half pipeline: stage A -> masks -> barrier -> issue stage B ->
// compute+store A (hides B latency) -> barrier -> compute+store B.
__global__ __launch_bounds__(256) void carafe_kernel(
    const float* __restrict__ feat, const float* __restrict__ masks,
    float* __restrict__ out) {
  __shared__ float sm[2 * HALFF];  // 2 halves x 16 ch x 320 f = 40 KB

  const int bid = blockIdx.x;
  const int cq = bid & 3;
  const int h  = (bid >> 2) & (HH - 1);
  const int n  = bid >> 8;
  const int t  = threadIdx.x;
  const int w  = t & (WW - 1);
  const int wv = t >> 6;

  const int y0 = min(max(h - 2, 0), HH - KK);  // clamp(h-2, 0, 59)

  // Stage 16 channels of half HX: each wave stages 4 channel slots,
  // 2 insts/slot (width16 = rows y0..y0+3, width4 = row y0+4). R13-proven.
#define STAGE(HX)                                                         \
  do {                                                                    \
    _Pragma("unroll")                                                     \
    for (int s = 0; s < 4; ++s) {                                         \
      const int cl = wv * 4 + s;                                          \
      const float* chg =                                                  \
          feat + ((size_t)(n * CC + cq * 32 + (HX) * 16 + cl) * HH + y0) * WW; \
      __builtin_amdgcn_global_load_lds(                                   \
          (const __attribute__((address_space(1))) void*)(chg + w * 4),   \
          (__attribute__((address_space(3))) void*)(sm + (HX) * HALFF + cl * SLOTF), \
          16, 0, 0);                                                      \
      __builtin_amdgcn_global_load_lds(                                   \
          (const __attribute__((address_space(1))) void*)(chg + 256 + w), \
          (__attribute__((address_space(3))) void*)(sm + (HX) * HALFF + cl * SLOTF + 256), \
          4, 0, 0);                                                       \
    }                                                                     \
  } while (0)

  STAGE(0);

  // --- masks -> registers with zero-padding validity folded in (proven);
  // overlaps stage-A latency. ---
  float vi[KK], vj[KK];
#pragma unroll
  for (int i = 0; i < KK; ++i) {
    const int r = h - 2 + i;
    vi[i] = (r >= 0 && r < HH) ? 1.f : 0.f;
    const int x = w - 2 + i;
    vj[i] = (x >= 0 && x < WW) ? 1.f : 0.f;
  }
  v2f mreg[K2][2];
#pragma unroll
  for (int k = 0; k < K2; ++k) {
    const int i = k / KK, j = k % KK;
    const float vv = vi[i] * vj[j];
#pragma unroll
    for (int a = 0; a < 2; ++a) {
      const float2 mv = *reinterpret_cast<const float2*>(
          &masks[(((size_t)n * K2 + k) * HUP + (2 * h + a)) * WUP + 2 * w]);
      v2f m; m.x = mv.x * vv; m.y = mv.y * vv;
      mreg[k][a] = m;
    }
  }

  // Row offsets within a staged slot (clamped; invalid rows vi-masked).
  int ri[KK];
#pragma unroll
  for (int i = 0; i < KK; ++i)
    ri[i] = min(max(h - 2 + i - y0, 0), KK - 1) * WW;

  const v4i srdO = make_srd(out, (unsigned)(NN * CC * HUP * WUP) * 4u);
  const int vob = (((n * CC + cq * 32 + wv) * HUP + 2 * h) * WUP + 2 * w) * 4;

#define FMA1(k, e)                                                       \
  do {                                                                   \
    v2f ff; ff.x = (e); ff.y = (e);                                      \
    acc0 += ff * mreg[k][0]; acc1 += ff * mreg[k][1];                    \
  } while (0)

  // Compute+store the 4 channels this thread owns in half HX (R13-proven
  // tap path: 5 ds_read_b32 + 20 DPP per channel).
#define COMPUTE(HX)                                                      \
  do {                                                                   \
    int cbase = (HX) * HALFF + wv * SLOTF + w;                           \
    int vobx = vob + (HX) * 16 * OCH;                                    \
    _Pragma("unroll 1")                                                  \
    for (int ci = 0; ci < 4; ++ci) {                                     \
      v2f acc0 = {0.f, 0.f}, acc1 = {0.f, 0.f};                          \
      _Pragma("unroll")                                                  \
      for (int i = 0; i < KK; ++i) {                                     \
        const float r  = sm[cbase + ri[i]];                              \
        const float m1 = dpp_prev1(r);                                   \
        const float m2 = dpp_prev1(m1);                                  \
        const float p1 = dpp_next1(r);                                   \
        const float p2 = dpp_next1(p1);                                  \
        FMA1(i * KK + 0, m2);                                            \
        FMA1(i * KK + 1, m1);                                            \
        FMA1(i * KK + 2, r);                                             \
        FMA1(i * KK + 3, p1);                                            \
        FMA1(i * KK + 4, p2);                                            \
      }                                                                  \
      llvm_amdgcn_raw_buffer_store_v2f32(acc0, srdO, vobx, 0, 0);        \
      llvm_amdgcn_raw_buffer_store_v2f32(acc1, srdO, vobx + WUP * 4, 0, 0); \
      cbase += 4 * SLOTF;                                                \
      vobx += 4 * OCH;                                                   \
    }                                                                    \
  } while (0)

  __syncthreads();   // stage A complete (vmcnt drained per wave + barrier)

  STAGE(1);          // B's HBM latency hides under compute/store of A

  COMPUTE(0);

  __syncthreads();   // stage B complete

  COMPUTE(1);

#undef COMPUTE
#undef FMA1
#undef STAGE
}

extern "C" void kernel_launch(void* const* d_in, const int* in_sizes, int n_in,
                              void* d_out, int out_size, void* d_ws, size_t ws_size,
                              hipStream_t stream) {
  const float* feat  = (const float*)d_in[0];
  const float* masks = (const float*)d_in[1];
  float* out = (float*)d_out;
  (void)in_sizes; (void)n_in; (void)out_size; (void)d_ws; (void)ws_size;
  carafe_kernel<<<NN * HH * 4, 256, 0, stream>>>(feat, masks, out);
}

// Round 15
// 19.450 us; speedup vs baseline: 1.0476x; 1.0476x over previous
//
#include <hip/hip_runtime.h>

#define NN 4
#define CC 128
#define HH 64
#define WW 64
#define KK 5
#define K2 25
#define HUP 128
#define WUP 128

typedef int   v4i __attribute__((ext_vector_type(4)));
typedef float v2f __attribute__((ext_vector_type(2)));

__device__ void llvm_amdgcn_raw_buffer_store_v2f32(v2f data, v4i srsrc,
                                                   int voffset, int soffset,
                                                   int aux)
    __asm("llvm.amdgcn.raw.buffer.store.v2f32");

__device__ inline v4i make_srd(const void* p, unsigned bytes) {
  union { const void* p; unsigned u[2]; } a;
  a.p = p;
  v4i r;
  r.x = (int)a.u[0];
  r.y = (int)(a.u[1] & 0xffffu);  // base[47:32], stride=0
  r.z = (int)bytes;               // num_records in bytes
  r.w = 0x00020000;               // raw dword access
  return r;
}

// DPP wave shifts (R13-proven):
//   wave_shr:1 (0x138): lane w reads w-1 (chain zeros lanes 0,1 = vj-masked).
//   wave_shl:1 (0x130): lane w reads w+1 (chain zeros lanes 62,63).
__device__ inline float dpp_prev1(float x) {  // lane w <- w-1
  return __int_as_float(__builtin_amdgcn_update_dpp(
      0, __float_as_int(x), 0x138, 0xf, 0xf, true));
}
__device__ inline float dpp_next1(float x) {  // lane w <- w+1
  return __int_as_float(__builtin_amdgcn_update_dpp(
      0, __float_as_int(x), 0x130, 0xf, 0xf, true));
}

// grid: NN*HH*4 = 1024 blocks, 256 threads, 40 KB LDS -> 4 blocks/CU.
//
// XCD-aware chunked swizzle (T1, bijective since 1024%8==0): HW round-robins
// consecutive HW block ids across the 8 XCDs, so remapping bid=(orig&7)*128
// + orig>>3 gives each XCD a CONTIGUOUS 128-block chunk = one n-quarter x 32
// consecutive h x all 4 cq. Per-XCD L2 working set ~2 MB (< 4 MB): the 5x
// h-overlap feature re-reads and 4x cq-sibling mask re-reads become L2 hits
// instead of L3/HBM round-trips.
//
// block: cq = bid&3, h = (bid>>2)&63, n = bid>>8
// thread: w = t&63 (output cols 2w,2w+1), cg = t>>6; c = cq*32 + ci*4 + cg
//
// R10/R11/R13 structure: single global->LDS staging exposure, LDS-fed loop;
// per window row ONE ds_read_b32 + 4 chained DPP wave shifts for the taps.
__global__ __launch_bounds__(256) void carafe_kernel(
    const float* __restrict__ feat, const float* __restrict__ masks,
    float* __restrict__ out) {
  __shared__ float sm[10240];  // 32 ch x 5 rows x 64 cols = 40 KB

  const int orig = blockIdx.x;
  const int bid = (orig & 7) * 128 + (orig >> 3);  // XCD chunk swizzle
  const int cq = bid & 3;
  const int h  = (bid >> 2) & (HH - 1);
  const int n  = bid >> 8;
  const int t  = threadIdx.x;
  const int w  = t & (WW - 1);
  const int wv = t >> 6;  // wave id = cg

  // --- stage: 5 consecutive in-bounds rows y0..y0+4 of 32 channels ---
  const int y0 = min(max(h - 2, 0), HH - KK);  // clamp(h-2, 0, 59)
#pragma unroll
  for (int s = 0; s < 8; ++s) {
    const int cl = wv * 8 + s;                 // channel slot in LDS
    const float* chg =
        feat + ((size_t)(n * CC + cq * 32 + cl) * HH + y0) * WW;
    __builtin_amdgcn_global_load_lds(
        (const __attribute__((address_space(1))) void*)(chg + w * 4),
        (__attribute__((address_space(3))) void*)(sm + cl * 320), 16, 0, 0);
    __builtin_amdgcn_global_load_lds(
        (const __attribute__((address_space(1))) void*)(chg + 256 + w),
        (__attribute__((address_space(3))) void*)(sm + cl * 320 + 256), 4, 0, 0);
  }

  // --- masks -> registers with zero-padding validity folded in (proven);
  // overlaps the staging latency. ---
  float vi[KK], vj[KK];
#pragma unroll
  for (int i = 0; i < KK; ++i) {
    const int r = h - 2 + i;
    vi[i] = (r >= 0 && r < HH) ? 1.f : 0.f;
    const int x = w - 2 + i;
    vj[i] = (x >= 0 && x < WW) ? 1.f : 0.f;
  }
  v2f mreg[K2][2];
#pragma unroll
  for (int k = 0; k < K2; ++k) {
    const int i = k / KK, j = k % KK;
    const float vv = vi[i] * vj[j];
#pragma unroll
    for (int a = 0; a < 2; ++a) {
      const float2 mv = *reinterpret_cast<const float2*>(
          &masks[(((size_t)n * K2 + k) * HUP + (2 * h + a)) * WUP + 2 * w]);
      v2f m; m.x = mv.x * vv; m.y = mv.y * vv;
      mreg[k][a] = m;
    }
  }

  // Row offsets within the staged tile (clamped; invalid rows vi-masked).
  int ri[KK];
#pragma unroll
  for (int i = 0; i < KK; ++i)
    ri[i] = min(max(h - 2 + i - y0, 0), KK - 1) * WW;

  const v4i srdO = make_srd(out, (unsigned)(NN * CC * HUP * WUP) * 4u);
  int vob = (((n * CC + cq * 32 + wv) * HUP + 2 * h) * WUP + 2 * w) * 4;

  __syncthreads();  // staging complete

#define FMA1(k, e)                                                       \
  do {                                                                   \
    v2f ff; ff.x = (e); ff.y = (e);                                      \
    acc0 += ff * mreg[k][0]; acc1 += ff * mreg[k][1];                    \
  } while (0)

  // --- compute: 8 channels per thread, 5 ds_read_b32 + 20 DPP per iter ---
  int cbase = wv * 320 + w;  // dword base of this thread's channel slot
#pragma unroll 1
  for (int ci = 0; ci < 8; ++ci) {
    v2f acc0 = {0.f, 0.f}, acc1 = {0.f, 0.f};
#pragma unroll
    for (int i = 0; i < KK; ++i) {
      const float r  = sm[cbase + ri[i]];   // lane w -> element w
      const float m1 = dpp_prev1(r);        // x = w-1
      const float m2 = dpp_prev1(m1);       // x = w-2
      const float p1 = dpp_next1(r);        // x = w+1
      const float p2 = dpp_next1(p1);       // x = w+2
      FMA1(i * KK + 0, m2);
      FMA1(i * KK + 1, m1);
      FMA1(i * KK + 2, r);
      FMA1(i * KK + 3, p1);
      FMA1(i * KK + 4, p2);
    }
    llvm_amdgcn_raw_buffer_store_v2f32(acc0, srdO, vob, 0, 0);
    llvm_amdgcn_raw_buffer_store_v2f32(acc1, srdO, vob + WUP * 4, 0, 0);

    cbase += 4 * 320;            // +4 channels (cg-interleaved)
    vob += 4 * HUP * WUP * 4;
  }
#undef FMA1
}

extern "C" void kernel_launch(void* const* d_in, const int* in_sizes, int n_in,
                              void* d_out, int out_size, void* d_ws, size_t ws_size,
                              hipStream_t stream) {
  const float* feat  = (const float*)d_in[0];
  const float* masks = (const float*)d_in[1];
  float* out = (float*)d_out;
  (void)in_sizes; (void)n_in; (void)out_size; (void)d_ws; (void)ws_size;
  carafe_kernel<<<NN * HH * 4, 256, 0, stream>>>(feat, masks, out);
}

// Round 16
// 18.179 us; speedup vs baseline: 1.1209x; 1.0699x over previous
//
#include <hip/hip_runtime.h>

#define NN 4
#define CC 128
#define HH 64
#define WW 64
#define KK 5
#define K2 25
#define HUP 128
#define WUP 128

typedef int   v4i __attribute__((ext_vector_type(4)));
typedef float v2f __attribute__((ext_vector_type(2)));

__device__ void llvm_amdgcn_raw_buffer_store_v2f32(v2f data, v4i srsrc,
                                                   int voffset, int soffset,
                                                   int aux)
    __asm("llvm.amdgcn.raw.buffer.store.v2f32");

__device__ inline v4i make_srd(const void* p, unsigned bytes) {
  union { const void* p; unsigned u[2]; } a;
  a.p = p;
  v4i r;
  r.x = (int)a.u[0];
  r.y = (int)(a.u[1] & 0xffffu);  // base[47:32], stride=0
  r.z = (int)bytes;               // num_records in bytes
  r.w = 0x00020000;               // raw dword access
  return r;
}

// DPP wave shifts (R13-proven):
//   wave_shr:1 (0x138): lane w reads w-1 (chain zeros lanes 0,1 = vj-masked).
//   wave_shl:1 (0x130): lane w reads w+1 (chain zeros lanes 62,63).
__device__ inline float dpp_prev1(float x) {  // lane w <- w-1
  return __int_as_float(__builtin_amdgcn_update_dpp(
      0, __float_as_int(x), 0x138, 0xf, 0xf, true));
}
__device__ inline float dpp_next1(float x) {  // lane w <- w+1
  return __int_as_float(__builtin_amdgcn_update_dpp(
      0, __float_as_int(x), 0x130, 0xf, 0xf, true));
}

// grid: NN*HH*4 = 1024 blocks, 256 threads, 66.5 KB LDS -> 2 blocks/CU.
// XCD chunk swizzle (R15-proven, bijective: 1024%8==0).
// block: cq = bid&3, h = (bid>>2)&63, n = bid>>8
// thread: w = t&63 (output cols 2w,2w+1), cg = t>>6; c = cq*32 + ci*4 + cg
//
// R16: masks staged cooperatively via global_load_lds (25 wave-insts/block,
// one 1KB slab per k = rows {2h,2h+1}) instead of 50 scattered float2 VMEM
// loads PER THREAD (4-wave-redundant). Cuts per-CU VMEM/TA instruction work
// ~2.5x; mreg is then built from LDS on the DS pipe (2-way conflict = free).
__global__ __launch_bounds__(256) void carafe_kernel(
    const float* __restrict__ feat, const float* __restrict__ masks,
    float* __restrict__ out) {
  __shared__ float sm[10240];   // features: 32 ch x 5 rows x 64 = 40 KB
  __shared__ float smm[6400];   // masks: 25 k x 2 rows x 128 wup = 25.6 KB

  const int orig = blockIdx.x;
  const int bid = (orig & 7) * 128 + (orig >> 3);  // XCD chunk swizzle
  const int cq = bid & 3;
  const int h  = (bid >> 2) & (HH - 1);
  const int n  = bid >> 8;
  const int t  = threadIdx.x;
  const int w  = t & (WW - 1);
  const int wv = t >> 6;  // wave id = cg

  // --- stage features: 5 consecutive in-bounds rows y0..y0+4, 32 ch ---
  const int y0 = min(max(h - 2, 0), HH - KK);  // clamp(h-2, 0, 59)
#pragma unroll
  for (int s = 0; s < 8; ++s) {
    const int cl = wv * 8 + s;                 // channel slot in LDS
    const float* chg =
        feat + ((size_t)(n * CC + cq * 32 + cl) * HH + y0) * WW;
    __builtin_amdgcn_global_load_lds(
        (const __attribute__((address_space(1))) void*)(chg + w * 4),
        (__attribute__((address_space(3))) void*)(sm + cl * 320), 16, 0, 0);
    __builtin_amdgcn_global_load_lds(
        (const __attribute__((address_space(1))) void*)(chg + 256 + w),
        (__attribute__((address_space(3))) void*)(sm + cl * 320 + 256), 4, 0, 0);
  }

  // --- stage masks: per k one 1KB slab masks[n,k,2h:2h+2,:] -> smm[k] ---
  // k = wv + 4*j distributes the 25 slabs across the 4 waves.
#pragma unroll
  for (int j = 0; j < 7; ++j) {
    const int k = wv + 4 * j;
    if (k < K2) {
      const float* mg = masks + (((size_t)n * K2 + k) * HUP + 2 * h) * WUP;
      __builtin_amdgcn_global_load_lds(
          (const __attribute__((address_space(1))) void*)(mg + w * 4),
          (__attribute__((address_space(3))) void*)(smm + k * 256), 16, 0, 0);
    }
  }

  // --- validity + row offsets (VALU, overlaps staging latency) ---
  float vi[KK], vj[KK];
#pragma unroll
  for (int i = 0; i < KK; ++i) {
    const int r = h - 2 + i;
    vi[i] = (r >= 0 && r < HH) ? 1.f : 0.f;
    const int x = w - 2 + i;
    vj[i] = (x >= 0 && x < WW) ? 1.f : 0.f;
  }
  int ri[KK];
#pragma unroll
  for (int i = 0; i < KK; ++i)
    ri[i] = min(max(h - 2 + i - y0, 0), KK - 1) * WW;

  const v4i srdO = make_srd(out, (unsigned)(NN * CC * HUP * WUP) * 4u);
  int vob = (((n * CC + cq * 32 + wv) * HUP + 2 * h) * WUP + 2 * w) * 4;

  __syncthreads();  // all staging complete

  // --- mreg from LDS: smm[k*256 + a*128 + 2w..2w+1] * vv ---
  v2f mreg[K2][2];
#pragma unroll
  for (int k = 0; k < K2; ++k) {
    const int i = k / KK, j = k % KK;
    const float vv = vi[i] * vj[j];
    const v2f u0 = *reinterpret_cast<const v2f*>(&smm[k * 256 + 2 * w]);
    const v2f u1 = *reinterpret_cast<const v2f*>(&smm[k * 256 + 128 + 2 * w]);
    mreg[k][0] = u0 * vv;
    mreg[k][1] = u1 * vv;
  }

#define FMA1(k, e)                                                       \
  do {                                                                   \
    v2f ff; ff.x = (e); ff.y = (e);                                      \
    acc0 += ff * mreg[k][0]; acc1 += ff * mreg[k][1];                    \
  } while (0)

  // --- compute: 8 channels per thread, 5 ds_read_b32 + 20 DPP per iter ---
  int cbase = wv * 320 + w;  // dword base of this thread's channel slot
#pragma unroll 1
  for (int ci = 0; ci < 8; ++ci) {
    v2f acc0 = {0.f, 0.f}, acc1 = {0.f, 0.f};
#pragma unroll
    for (int i = 0; i < KK; ++i) {
      const float r  = sm[cbase + ri[i]];   // lane w -> element w
      const float m1 = dpp_prev1(r);        // x = w-1
      const float m2 = dpp_prev1(m1);       // x = w-2
      const float p1 = dpp_next1(r);        // x = w+1
      const float p2 = dpp_next1(p1);       // x = w+2
      FMA1(i * KK + 0, m2);
      FMA1(i * KK + 1, m1);
      FMA1(i * KK + 2, r);
      FMA1(i * KK + 3, p1);
      FMA1(i * KK + 4, p2);
    }
    llvm_amdgcn_raw_buffer_store_v2f32(acc0, srdO, vob, 0, 0);
    llvm_amdgcn_raw_buffer_store_v2f32(acc1, srdO, vob + WUP * 4, 0, 0);

    cbase += 4 * 320;            // +4 channels (cg-interleaved)
    vob += 4 * HUP * WUP * 4;
  }
#undef FMA1
}

extern "C" void kernel_launch(void* const* d_in, const int* in_sizes, int n_in,
                              void* d_out, int out_size, void* d_ws, size_t ws_size,
                              hipStream_t stream) {
  const float* feat  = (const float*)d_in[0];
  const float* masks = (const float*)d_in[1];
  float* out = (float*)d_out;
  (void)in_sizes; (void)n_in; (void)out_size; (void)d_ws; (void)ws_size;
  carafe_kernel<<<NN * HH * 4, 256, 0, stream>>>(feat, masks, out);
}

// Round 17
// 17.893 us; speedup vs baseline: 1.1388x; 1.0160x over previous
//
#include <hip/hip_runtime.h>

#define NN 4
#define CC 128
#define HH 64
#define WW 64
#define KK 5
#define K2 25
#define HUP 128
#define WUP 128

typedef int   v4i __attribute__((ext_vector_type(4)));
typedef float v2f __attribute__((ext_vector_type(2)));

__device__ void llvm_amdgcn_raw_buffer_store_v2f32(v2f data, v4i srsrc,
                                                   int voffset, int soffset,
                                                   int aux)
    __asm("llvm.amdgcn.raw.buffer.store.v2f32");

__device__ inline v4i make_srd(const void* p, unsigned bytes) {
  union { const void* p; unsigned u[2]; } a;
  a.p = p;
  v4i r;
  r.x = (int)a.u[0];
  r.y = (int)(a.u[1] & 0xffffu);  // base[47:32], stride=0
  r.z = (int)bytes;               // num_records in bytes
  r.w = 0x00020000;               // raw dword access
  return r;
}

// DPP wave shifts (R13-proven):
//   wave_shr:1 (0x138): lane w reads w-1 (chain zeros lanes 0,1 = vj-masked).
//   wave_shl:1 (0x130): lane w reads w+1 (chain zeros lanes 62,63).
__device__ inline float dpp_prev1(float x) {  // lane w <- w-1
  return __int_as_float(__builtin_amdgcn_update_dpp(
      0, __float_as_int(x), 0x138, 0xf, 0xf, true));
}
__device__ inline float dpp_next1(float x) {  // lane w <- w+1
  return __int_as_float(__builtin_amdgcn_update_dpp(
      0, __float_as_int(x), 0x130, 0xf, 0xf, true));
}

// grid: NN*HH*4 = 1024 blocks, 256 threads, 66.5 KB LDS -> 2 blocks/CU.
// XCD chunk swizzle (R15-proven). block: cq=bid&3, h=(bid>>2)&63, n=bid>>8.
// thread: w = t&63 (output cols 2w,2w+1), wv = t>>6; c = cq*32 + ci*4 + wv.
//
// R17: LDS slot i ALWAYS holds tap-i's (pre-clamped) feature row, so compute
// tap offsets are the compile-time constants i*64 -> ds_read2_b32 fusion
// (5->3 DS insts/row-set) and no ri[] VALU. Interior blocks (h in [2,61])
// stage 5 contiguous rows with 2 wide glds insts; edge blocks stage per-row
// clamped (5 insts/slot). Compute loop unroll 2 overlaps next iter's LDS
// reads with current FMAs.
__global__ __launch_bounds__(256) void carafe_kernel(
    const float* __restrict__ feat, const float* __restrict__ masks,
    float* __restrict__ out) {
  __shared__ float sm[10240];   // features: 32 ch x 5 rows x 64 = 40 KB
  __shared__ float smm[6400];   // masks: 25 k x 2 rows x 128 wup = 25.6 KB

  const int orig = blockIdx.x;
  const int bid = (orig & 7) * 128 + (orig >> 3);  // XCD chunk swizzle
  const int cq = bid & 3;
  const int h  = (bid >> 2) & (HH - 1);
  const int n  = bid >> 8;
  const int t  = threadIdx.x;
  const int w  = t & (WW - 1);
  const int wv = t >> 6;  // wave id = cg

  // --- stage features: slot i = row clamp(h-2+i, 0, 63) of each channel ---
  if (h >= 2 && h <= HH - 3) {
    // interior: rows h-2..h+2 contiguous -> width16 (rows 0..3) + width4
    const int y0 = h - 2;
#pragma unroll
    for (int s = 0; s < 8; ++s) {
      const int cl = wv * 8 + s;
      const float* chg =
          feat + ((size_t)(n * CC + cq * 32 + cl) * HH + y0) * WW;
      __builtin_amdgcn_global_load_lds(
          (const __attribute__((address_space(1))) void*)(chg + w * 4),
          (__attribute__((address_space(3))) void*)(sm + cl * 320), 16, 0, 0);
      __builtin_amdgcn_global_load_lds(
          (const __attribute__((address_space(1))) void*)(chg + 256 + w),
          (__attribute__((address_space(3))) void*)(sm + cl * 320 + 256), 4, 0, 0);
    }
  } else {
    // edge: per-row clamped staging (slot i <- row clamp(h-2+i,0,63));
    // invalid taps are vi-masked, duplicated rows harmless.
#pragma unroll
    for (int s = 0; s < 8; ++s) {
      const int cl = wv * 8 + s;
      const float* chb = feat + (size_t)(n * CC + cq * 32 + cl) * (HH * WW);
#pragma unroll
      for (int i = 0; i < KK; ++i) {
        const int r = min(max(h - 2 + i, 0), HH - 1);
        __builtin_amdgcn_global_load_lds(
            (const __attribute__((address_space(1))) void*)(chb + r * WW + w),
            (__attribute__((address_space(3))) void*)(sm + cl * 320 + i * 64),
            4, 0, 0);
      }
    }
  }

  // --- stage masks: per k one 1KB slab masks[n,k,2h:2h+2,:] -> smm[k] ---
#pragma unroll
  for (int j = 0; j < 7; ++j) {
    const int k = wv + 4 * j;
    if (k < K2) {
      const float* mg = masks + (((size_t)n * K2 + k) * HUP + 2 * h) * WUP;
      __builtin_amdgcn_global_load_lds(
          (const __attribute__((address_space(1))) void*)(mg + w * 4),
          (__attribute__((address_space(3))) void*)(smm + k * 256), 16, 0, 0);
    }
  }

  // --- validity (VALU, overlaps staging latency) ---
  float vi[KK], vj[KK];
#pragma unroll
  for (int i = 0; i < KK; ++i) {
    const int r = h - 2 + i;
    vi[i] = (r >= 0 && r < HH) ? 1.f : 0.f;
    const int x = w - 2 + i;
    vj[i] = (x >= 0 && x < WW) ? 1.f : 0.f;
  }

  const v4i srdO = make_srd(out, (unsigned)(NN * CC * HUP * WUP) * 4u);
  int vob = (((n * CC + cq * 32 + wv) * HUP + 2 * h) * WUP + 2 * w) * 4;

  __syncthreads();  // all staging complete

  // --- mreg from LDS: smm[k*256 + a*128 + 2w..2w+1] * vv ---
  v2f mreg[K2][2];
#pragma unroll
  for (int k = 0; k < K2; ++k) {
    const int i = k / KK, j = k % KK;
    const float vv = vi[i] * vj[j];
    const v2f u0 = *reinterpret_cast<const v2f*>(&smm[k * 256 + 2 * w]);
    const v2f u1 = *reinterpret_cast<const v2f*>(&smm[k * 256 + 128 + 2 * w]);
    mreg[k][0] = u0 * vv;
    mreg[k][1] = u1 * vv;
  }

#define FMA1(k, e)                                                       \
  do {                                                                   \
    v2f ff; ff.x = (e); ff.y = (e);                                      \
    acc0 += ff * mreg[k][0]; acc1 += ff * mreg[k][1];                    \
  } while (0)

  // --- compute: 8 channels/thread; static tap offsets i*64 ->
  // 2x ds_read2_b32 + 1x ds_read_b32 per row-set; unroll 2 for overlap ---
  int cbase = wv * 320 + w;  // dword base of this thread's channel slot
#pragma unroll 2
  for (int ci = 0; ci < 8; ++ci) {
    v2f acc0 = {0.f, 0.f}, acc1 = {0.f, 0.f};
#pragma unroll
    for (int i = 0; i < KK; ++i) {
      const float r  = sm[cbase + i * 64];  // lane w -> element w of slot i
      const float m1 = dpp_prev1(r);        // x = w-1
      const float m2 = dpp_prev1(m1);       // x = w-2
      const float p1 = dpp_next1(r);        // x = w+1
      const float p2 = dpp_next1(p1);       // x = w+2
      FMA1(i * KK + 0, m2);
      FMA1(i * KK + 1, m1);
      FMA1(i * KK + 2, r);
      FMA1(i * KK + 3, p1);
      FMA1(i * KK + 4, p2);
    }
    llvm_amdgcn_raw_buffer_store_v2f32(acc0, srdO, vob, 0, 0);
    llvm_amdgcn_raw_buffer_store_v2f32(acc1, srdO, vob + WUP * 4, 0, 0);

    cbase += 4 * 320;            // +4 channels (cg-interleaved)
    vob += 4 * HUP * WUP * 4;
  }
#undef FMA1
}

extern "C" void kernel_launch(void* const* d_in, const int* in_sizes, int n_in,
                              void* d_out, int out_size, void* d_ws, size_t ws_size,
                              hipStream_t stream) {
  const float* feat  = (const float*)d_in[0];
  const float* masks = (const float*)d_in[1];
  float* out = (float*)d_out;
  (void)in_sizes; (void)n_in; (void)out_size; (void)d_ws; (void)ws_size;
  carafe_kernel<<<NN * HH * 4, 256, 0, stream>>>(feat, masks, out);
}